// Round 5
// baseline (405.430 us; speedup 1.0000x reference)
//
#include <hip/hip_runtime.h>
#include <cstdint>
#include <cstddef>

#define B_DIM 512
#define T_DIM 200
#define D_DIM 512
#define NPAD  208   // N padded to 13*16
#define NKG   28    // K padded to 224 = 28 groups of 8
#define NT    13    // n-tiles of 16
#define KS_STEPS 7  // 224 / 32

typedef short  short8  __attribute__((ext_vector_type(8)));
typedef float  floatx4 __attribute__((ext_vector_type(4)));

__device__ __forceinline__ unsigned short f2bf(float f) {
  unsigned int u = __float_as_uint(f);
  u += 0x7fffu + ((u >> 16) & 1u);   // round-to-nearest-even
  return (unsigned short)(u >> 16);
}
__device__ __forceinline__ float bf2f(unsigned short h) {
  return __uint_as_float(((unsigned int)h) << 16);
}

// W (200x200 fp32) -> bf16, padded 224x208, B-fragment layout [k/8][n][k%8]
__global__ void prep_w_kernel(const float* __restrict__ W,
                              unsigned short* __restrict__ wf) {
  int idx = blockIdx.x * blockDim.x + threadIdx.x;
  if (idx >= NKG * 8 * NPAD) return;
  int k = idx / NPAD;
  int n = idx - k * NPAD;
  float v = (k < T_DIM && n < T_DIM) ? W[k * T_DIM + n] : 0.0f;
  wf[((size_t)(k >> 3) * NPAD + n) * 8 + (k & 7)] = f2bf(v);
}

// Wave-autonomous design: each wave owns a 16-row d-tile of one batch item.
// Its lanes' strided X loads ARE its A-fragment elements; LDS slice is
// wave-private (final-dot t-reads only) -> NO __syncthreads anywhere.
__global__ __launch_bounds__(256, 5)
void attn_kernel(const float* __restrict__ X,
                 const unsigned short* __restrict__ wf,
                 const float* __restrict__ bias,
                 float* __restrict__ out) {
  // per-wave slice: [kg 0..27][m 0..15][j 0..7] bf16 = 7168 B; x4 waves = 28,672 B
  __shared__ __align__(16) unsigned short Xa[4 * NKG * 16 * 8];

  const int tid  = threadIdx.x;
  const int wv   = tid >> 6;
  const int lane = tid & 63;
  const int l15  = lane & 15;
  const int g    = lane >> 4;

  const int gw = blockIdx.x * 4 + wv;   // global wave id
  const int bb = gw >> 5;               // batch item
  const int d0 = (gw & 31) << 4;        // d-tile origin

  unsigned short* Xw = Xa + wv * (NKG * 16 * 8);
  const float* xbase = X + (size_t)bb * T_DIM * D_DIM + d0 + l15;

  // ---- staging: 2-deep pipelined strided loads; lane (g,l15) loads exactly
  // its A-frag elements t = ks*32+g*8+j at column d0+l15.
  float cur[8], nxt[8];
  {
    const float* p = xbase + (size_t)(g * 8) * D_DIM;
    #pragma unroll
    for (int j = 0; j < 8; ++j) cur[j] = p[(size_t)j * D_DIM];
  }
  #pragma unroll
  for (int ks = 0; ks < KS_STEPS; ++ks) {
    if (ks < 6) {
      // ks==5 prefetches the ks==6 rows t=192+g*8+j: only g==0 is in-bounds
      // (t=192..199 < 200). g>=1 must NOT issue the load (OOB for bb=511).
      if (ks < 5 || g == 0) {
        const float* p = xbase + (size_t)((ks + 1) * 32 + g * 8) * D_DIM;
        #pragma unroll
        for (int j = 0; j < 8; ++j) nxt[j] = p[(size_t)j * D_DIM];
      } else {
        #pragma unroll
        for (int j = 0; j < 8; ++j) nxt[j] = 0.0f;
      }
    }
    int4 w;
    w.x = (int)f2bf(cur[0]) | ((int)f2bf(cur[1]) << 16);
    w.y = (int)f2bf(cur[2]) | ((int)f2bf(cur[3]) << 16);
    w.z = (int)f2bf(cur[4]) | ((int)f2bf(cur[5]) << 16);
    w.w = (int)f2bf(cur[6]) | ((int)f2bf(cur[7]) << 16);
    *(int4*)&Xw[(((ks * 4 + g) * 16) + l15) * 8] = w;  // ds_write_b128
    #pragma unroll
    for (int j = 0; j < 8; ++j) cur[j] = nxt[j];
  }

  floatx4 acc[NT];
  #pragma unroll
  for (int nt = 0; nt < NT; ++nt)
    acc[nt] = (floatx4){0.f, 0.f, 0.f, 0.f};

  // ---- K-loop: A-frags from own LDS slice (no barrier needed — same-wave
  // DS ordering via lgkmcnt), B-frags stream from L2-resident wf.
  #pragma unroll
  for (int ks = 0; ks < KS_STEPS; ++ks) {
    const int kg = ks * 4 + g;
    short8 a = *(const short8*)&Xw[((kg * 16) + l15) * 8];
    const unsigned short* wp = wf + ((size_t)kg * NPAD + l15) * 8;
    #pragma unroll
    for (int nt = 0; nt < NT; ++nt) {
      short8 bfr = *(const short8*)(wp + nt * 16 * 8);
      acc[nt] = __builtin_amdgcn_mfma_f32_16x16x32_bf16(a, bfr, acc[nt], 0, 0, 0);
    }
  }

  // ---- fused epilogue: p = exp(tanh(z)); tanh bounded in [-1,1] => softmax
  // needs no max pass (exp in [0.37,2.72], sum in [73,544]).
  // C/D layout: col = lane&15 (= t within tile), row m = g*4 + r.
  float part[4] = {0.f, 0.f, 0.f, 0.f};
  float rs[4]   = {0.f, 0.f, 0.f, 0.f};
  #pragma unroll
  for (int nt = 0; nt < NT; ++nt) {
    const int t = nt * 16 + l15;
    const bool valid = (t < T_DIM);
    const float bvn = valid ? bias[t] : 0.0f;   // bias indexed by n == t here
    const unsigned short* xp = &Xw[((t >> 3) * 16) * 8 + (t & 7)];
    #pragma unroll
    for (int r = 0; r < 4; ++r) {
      if (valid) {
        float z  = acc[nt][r] + bvn;
        float e  = __expf(2.0f * z);              // tanh = 1 - 2/(e^{2z}+1)
        float th = 1.0f - __fdividef(2.0f, e + 1.0f);
        float p  = __expf(th);
        rs[r]   += p;
        const int m = g * 4 + r;
        part[r] += p * bf2f(xp[m * 8]);           // X[t][d0+m]
      }
    }
  }
  // reduce over the 16 t-lanes (each (g,r) is a distinct output row)
  #pragma unroll
  for (int off = 1; off <= 8; off <<= 1)
    #pragma unroll
    for (int r = 0; r < 4; ++r) {
      part[r] += __shfl_xor(part[r], off, 16);
      rs[r]   += __shfl_xor(rs[r],   off, 16);
    }

  if (l15 == 0) {
    #pragma unroll
    for (int r = 0; r < 4; ++r)
      out[(size_t)bb * D_DIM + d0 + g * 4 + r] = part[r] * __frcp_rn(rs[r]);
  }
}

extern "C" void kernel_launch(void* const* d_in, const int* in_sizes, int n_in,
                              void* d_out, int out_size, void* d_ws, size_t ws_size,
                              hipStream_t stream) {
  const float* X  = (const float*)d_in[0];
  const float* W  = (const float*)d_in[1];
  const float* bs = (const float*)d_in[2];
  float* out = (float*)d_out;
  unsigned short* wf = (unsigned short*)d_ws;  // needs 224*208*2 = 93,184 B

  const int wtot = NKG * 8 * NPAD;
  hipLaunchKernelGGL(prep_w_kernel, dim3((wtot + 255) / 256), dim3(256), 0, stream,
                     W, wf);
  // 16384 waves = 512 b * 32 d-tiles; 4 autonomous waves per block
  hipLaunchKernelGGL(attn_kernel, dim3(4096), dim3(256), 0, stream,
                     X, wf, bs, out);
}

// Round 6
// 342.138 us; speedup vs baseline: 1.1850x; 1.1850x over previous
//
#include <hip/hip_runtime.h>
#include <cstdint>
#include <cstddef>

#define B_DIM 512
#define T_DIM 200
#define D_DIM 512
#define NPAD  208   // N padded to 13*16
#define NKG   28    // K padded to 224 = 28 groups of 8
#define NT    13    // n-tiles of 16
#define KS_STEPS 7  // 224 / 32

typedef short  short8  __attribute__((ext_vector_type(8)));
typedef float  floatx4 __attribute__((ext_vector_type(4)));

__device__ __forceinline__ unsigned short f2bf(float f) {
  unsigned int u = __float_as_uint(f);
  u += 0x7fffu + ((u >> 16) & 1u);   // round-to-nearest-even
  return (unsigned short)(u >> 16);
}
__device__ __forceinline__ float bf2f(unsigned short h) {
  return __uint_as_float(((unsigned int)h) << 16);
}

// W (200x200 fp32) -> bf16, padded 224x208, B-fragment layout [k/8][n][k%8]
__global__ void prep_w_kernel(const float* __restrict__ W,
                              unsigned short* __restrict__ wf) {
  int idx = blockIdx.x * blockDim.x + threadIdx.x;
  if (idx >= NKG * 8 * NPAD) return;
  int k = idx / NPAD;
  int n = idx - k * NPAD;
  float v = (k < T_DIM && n < T_DIM) ? W[k * T_DIM + n] : 0.0f;
  wf[((size_t)(k >> 3) * NPAD + n) * 8 + (k & 7)] = f2bf(v);
}

// Wave-autonomous design: each wave owns a 16-row d-tile of one batch item.
// Its lanes' strided X loads ARE its A-fragment elements; LDS slice is
// wave-private (final-dot t-reads only) -> NO __syncthreads anywhere.
// launch_bounds(256,4): 128-reg budget. (256,5) spilled ~25 regs/lane ->
// 107 MB scratch writes, 234 us (R5). Reg demand is ~120: acc 52 + pipe 16 + misc.
__global__ __launch_bounds__(256, 4)
void attn_kernel(const float* __restrict__ X,
                 const unsigned short* __restrict__ wf,
                 const float* __restrict__ bias,
                 float* __restrict__ out) {
  // per-wave slice: [kg 0..27][m 0..15][j 0..7] bf16 = 7168 B; x4 waves = 28,672 B
  __shared__ __align__(16) unsigned short Xa[4 * NKG * 16 * 8];

  const int tid  = threadIdx.x;
  const int wv   = tid >> 6;
  const int lane = tid & 63;
  const int l15  = lane & 15;
  const int g    = lane >> 4;

  const int gw = blockIdx.x * 4 + wv;   // global wave id
  const int bb = gw >> 5;               // batch item
  const int d0 = (gw & 31) << 4;        // d-tile origin

  unsigned short* Xw = Xa + wv * (NKG * 16 * 8);
  const float* xbase = X + (size_t)bb * T_DIM * D_DIM + d0 + l15;

  // ---- staging: 2-deep pipelined strided loads; lane (g,l15) loads exactly
  // its A-frag elements t = ks*32+g*8+j at column d0+l15.
  float cur[8], nxt[8];
  {
    const float* p = xbase + (size_t)(g * 8) * D_DIM;
    #pragma unroll
    for (int j = 0; j < 8; ++j) cur[j] = p[(size_t)j * D_DIM];
  }
  #pragma unroll
  for (int ks = 0; ks < KS_STEPS; ++ks) {
    if (ks < 6) {
      // ks==5 prefetches the ks==6 rows t=192+g*8+j: only g==0 is in-bounds
      // (t=192..199 < 200). g>=1 must NOT issue the load (OOB for bb=511).
      if (ks < 5 || g == 0) {
        const float* p = xbase + (size_t)((ks + 1) * 32 + g * 8) * D_DIM;
        #pragma unroll
        for (int j = 0; j < 8; ++j) nxt[j] = p[(size_t)j * D_DIM];
      } else {
        #pragma unroll
        for (int j = 0; j < 8; ++j) nxt[j] = 0.0f;
      }
    }
    int4 w;
    w.x = (int)f2bf(cur[0]) | ((int)f2bf(cur[1]) << 16);
    w.y = (int)f2bf(cur[2]) | ((int)f2bf(cur[3]) << 16);
    w.z = (int)f2bf(cur[4]) | ((int)f2bf(cur[5]) << 16);
    w.w = (int)f2bf(cur[6]) | ((int)f2bf(cur[7]) << 16);
    *(int4*)&Xw[(((ks * 4 + g) * 16) + l15) * 8] = w;  // ds_write_b128
    #pragma unroll
    for (int j = 0; j < 8; ++j) cur[j] = nxt[j];
  }

  floatx4 acc[NT];
  #pragma unroll
  for (int nt = 0; nt < NT; ++nt)
    acc[nt] = (floatx4){0.f, 0.f, 0.f, 0.f};

  // ---- K-loop: A-frags from own LDS slice (no barrier needed — same-wave
  // DS ordering via lgkmcnt), B-frags stream from L2-resident wf.
  #pragma unroll
  for (int ks = 0; ks < KS_STEPS; ++ks) {
    const int kg = ks * 4 + g;
    short8 a = *(const short8*)&Xw[((kg * 16) + l15) * 8];
    const unsigned short* wp = wf + ((size_t)kg * NPAD + l15) * 8;
    #pragma unroll
    for (int nt = 0; nt < NT; ++nt) {
      short8 bfr = *(const short8*)(wp + nt * 16 * 8);
      acc[nt] = __builtin_amdgcn_mfma_f32_16x16x32_bf16(a, bfr, acc[nt], 0, 0, 0);
    }
  }

  // ---- fused epilogue: p = exp(tanh(z)); tanh bounded in [-1,1] => softmax
  // needs no max pass (exp in [0.37,2.72], sum in [73,544]).
  // C/D layout: col = lane&15 (= t within tile), row m = g*4 + r.
  float part[4] = {0.f, 0.f, 0.f, 0.f};
  float rs[4]   = {0.f, 0.f, 0.f, 0.f};
  #pragma unroll
  for (int nt = 0; nt < NT; ++nt) {
    const int t = nt * 16 + l15;
    const bool valid = (t < T_DIM);
    const float bvn = valid ? bias[t] : 0.0f;   // bias indexed by n == t here
    const unsigned short* xp = &Xw[((t >> 3) * 16) * 8 + (t & 7)];
    #pragma unroll
    for (int r = 0; r < 4; ++r) {
      if (valid) {
        float z  = acc[nt][r] + bvn;
        float e  = __expf(2.0f * z);              // tanh = 1 - 2/(e^{2z}+1)
        float th = 1.0f - __fdividef(2.0f, e + 1.0f);
        float p  = __expf(th);
        rs[r]   += p;
        const int m = g * 4 + r;
        part[r] += p * bf2f(xp[m * 8]);           // X[t][d0+m]
      }
    }
  }
  // reduce over the 16 t-lanes (each (g,r) is a distinct output row)
  #pragma unroll
  for (int off = 1; off <= 8; off <<= 1)
    #pragma unroll
    for (int r = 0; r < 4; ++r) {
      part[r] += __shfl_xor(part[r], off, 16);
      rs[r]   += __shfl_xor(rs[r],   off, 16);
    }

  if (l15 == 0) {
    #pragma unroll
    for (int r = 0; r < 4; ++r)
      out[(size_t)bb * D_DIM + d0 + g * 4 + r] = part[r] * __frcp_rn(rs[r]);
  }
}

extern "C" void kernel_launch(void* const* d_in, const int* in_sizes, int n_in,
                              void* d_out, int out_size, void* d_ws, size_t ws_size,
                              hipStream_t stream) {
  const float* X  = (const float*)d_in[0];
  const float* W  = (const float*)d_in[1];
  const float* bs = (const float*)d_in[2];
  float* out = (float*)d_out;
  unsigned short* wf = (unsigned short*)d_ws;  // needs 224*208*2 = 93,184 B

  const int wtot = NKG * 8 * NPAD;
  hipLaunchKernelGGL(prep_w_kernel, dim3((wtot + 255) / 256), dim3(256), 0, stream,
                     W, wf);
  // 16384 waves = 512 b * 32 d-tiles; 4 autonomous waves per block
  hipLaunchKernelGGL(attn_kernel, dim3(4096), dim3(256), 0, stream,
                     X, wf, bs, out);
}